// Round 1
// baseline (574.375 us; speedup 1.0000x reference)
//
#include <hip/hip_runtime.h>

#define BS 512
#define SL 1024
#define NC 64

// ---------------------------------------------------------------------------
// Kernel 1: init output — out[0] = 0 (loss accumulator), out[1..4096] = T copy
// ---------------------------------------------------------------------------
__global__ __launch_bounds__(256) void crf_init_out(const float* __restrict__ trans,
                                                    float* __restrict__ out) {
    int idx = blockIdx.x * 256 + threadIdx.x;
    if (idx == 0) out[0] = 0.0f;
    if (idx < NC * NC) out[1 + idx] = trans[idx];
}

// ---------------------------------------------------------------------------
// Kernel 2: one wave (64 lanes) per batch element. Lane c owns class c.
//   alpha_c updated via: a0 = alpha[lane0]; p_i = exp(alpha_i - a0);
//   s_c = sum_i p_i * E[i][c];  alpha_c = x_c + a0 + log(s_c)
// Fused unary/binary accumulation; loop stops at len (masked steps frozen).
// ---------------------------------------------------------------------------
__global__ __launch_bounds__(64) void crf_fwd(const float* __restrict__ inputs,
                                              const int* __restrict__ masks,
                                              const int* __restrict__ tags,
                                              const float* __restrict__ trans,
                                              float* __restrict__ out) {
    const int b = blockIdx.x;
    const int lane = threadIdx.x;

    __shared__ float Tlds[NC * NC];   // raw transitions for binary lookup
    __shared__ float plds[NC];        // p broadcast buffer
    __shared__ float red[NC];         // reduction scratch
    __shared__ int   taglds[SL];
    __shared__ int   lenlds;

    const float* __restrict__ inrow = inputs + (size_t)b * SL * NC;

    // Stage T into LDS and E = exp(T) column into registers (lane c holds E[:,c])
    float E[NC];
#pragma unroll
    for (int i = 0; i < NC; ++i) {
        float tv = trans[i * NC + lane];   // coalesced row read
        Tlds[i * NC + lane] = tv;
        E[i] = __expf(tv);
    }

    // Stage tags; compute len = #unmasked = lengths[b]
    int cnt = 0;
#pragma unroll
    for (int k = 0; k < SL / NC; ++k) {
        int idx = k * NC + lane;
        taglds[idx] = tags[(size_t)b * SL + idx];
        cnt += (masks[(size_t)b * SL + idx] == 0) ? 1 : 0;
    }
    red[lane] = (float)cnt;
    __syncthreads();
    if (lane == 0) {
        int s = 0;
        for (int i = 0; i < NC; ++i) s += (int)red[i];
        lenlds = s;
    }
    __syncthreads();
    const int len = lenlds;   // >= SL/2 >= 1 by construction

    // t = 0
    float x = inrow[lane];
    float alpha = x;
    int tagprev = taglds[0];
    float u = (lane == tagprev) ? x : 0.0f;   // unary partial (only owning lane adds)
    float bacc = 0.0f;                        // binary acc (uniform across lanes)

    float xcur = inrow[NC + lane];            // prefetch row t=1 (len>=512 so valid)

    for (int t = 1; t < len; ++t) {
        // prefetch next row (clamp: t+1 can be == len == SL)
        int tn = t + 1; if (tn > SL - 1) tn = SL - 1;
        float xnext = inrow[tn * NC + lane];

        float a0 = __int_as_float(__builtin_amdgcn_readfirstlane(__float_as_int(alpha)));
        float p = __expf(alpha - a0);
        plds[lane] = p;
        __syncthreads();

        float s0 = 0.f, s1 = 0.f, s2 = 0.f, s3 = 0.f;
#pragma unroll
        for (int j = 0; j < NC / 4; ++j) {
            float4 pv = ((const float4*)plds)[j];   // same-address broadcast read
            s0 = fmaf(pv.x, E[4 * j + 0], s0);
            s1 = fmaf(pv.y, E[4 * j + 1], s1);
            s2 = fmaf(pv.z, E[4 * j + 2], s2);
            s3 = fmaf(pv.w, E[4 * j + 3], s3);
        }
        float s = (s0 + s1) + (s2 + s3);

        int tg = taglds[t];                       // uniform broadcast
        bacc += Tlds[tagprev * NC + tg];          // uniform broadcast
        u += (lane == tg) ? xcur : 0.0f;

        alpha = xcur + a0 + __logf(s);
        tagprev = tg;
        xcur = xnext;
        __syncthreads();   // protect plds before next iteration's write
    }

    // log_norm = logsumexp over lanes of alpha
    float a0 = __int_as_float(__builtin_amdgcn_readfirstlane(__float_as_int(alpha)));
    plds[lane] = __expf(alpha - a0);
    red[lane] = u;
    __syncthreads();
    float s0 = 0.f, s1 = 0.f, s2 = 0.f, s3 = 0.f;
#pragma unroll
    for (int j = 0; j < NC / 4; ++j) {
        float4 pv = ((const float4*)plds)[j];
        s0 += pv.x; s1 += pv.y; s2 += pv.z; s3 += pv.w;
    }
    float log_norm = a0 + __logf((s0 + s1) + (s2 + s3));

    if (lane == 0) {
        float usum = 0.f;
        for (int i = 0; i < NC; ++i) usum += red[i];
        float ll = usum + bacc - log_norm;        // log_likelihood
        atomicAdd(out, -ll * (1.0f / BS));        // loss = sum(-ll)/BS
    }
}

// ---------------------------------------------------------------------------
extern "C" void kernel_launch(void* const* d_in, const int* in_sizes, int n_in,
                              void* d_out, int out_size, void* d_ws, size_t ws_size,
                              hipStream_t stream) {
    const float* inputs = (const float*)d_in[0];
    const int*   masks  = (const int*)d_in[1];
    const int*   tags   = (const int*)d_in[2];
    const float* trans  = (const float*)d_in[3];
    float* out = (float*)d_out;

    crf_init_out<<<(1 + NC * NC + 255) / 256, 256, 0, stream>>>(trans, out);
    crf_fwd<<<BS, 64, 0, stream>>>(inputs, masks, tags, trans, out);
}